// Round 2
// baseline (18.984 us; speedup 1.0000x reference)
//
#include <hip/hip_runtime.h>

#define N_ROWS 524288
#define F 32
#define NB 255            // branches; heap node id == branch id for perfect tree
#define DEPTH 8
#define ROWS_PER_BLOCK 256
#define XSTRIDE 36        // padded floats per LDS row (144 B: 16B-aligned, conflict-breaking)

__global__ __launch_bounds__(256) void tree_traverse_kernel(
    const float* __restrict__ x,
    const int*   __restrict__ feature,
    const float* __restrict__ threshold,
    const float* __restrict__ value,
    float*       __restrict__ out)
{
    __shared__ float xs[ROWS_PER_BLOCK * XSTRIDE];
    __shared__ float s_thr[256];
    __shared__ int   s_feat[256];

    const int tid = threadIdx.x;
    const long long block_row0 = (long long)blockIdx.x * ROWS_PER_BLOCK;

    // Stage node tables (255 entries) into LDS.
    if (tid < NB) {
        s_feat[tid] = feature[tid];
        s_thr[tid]  = threshold[tid];
    }

    // Stage x tile: 256 rows x 32 floats = 2048 float4, coalesced.
    const float4* xg = reinterpret_cast<const float4*>(x + block_row0 * F);
    #pragma unroll
    for (int k = 0; k < 8; ++k) {
        int idx = tid + k * 256;      // float4 index within tile
        float4 v = xg[idx];
        int row = idx >> 3;           // 8 float4 per row
        int f4  = idx & 7;
        *reinterpret_cast<float4*>(&xs[row * XSTRIDE + f4 * 4]) = v;  // 16B aligned
    }

    __syncthreads();

    // Heap traversal: 8 dependent steps, all operands in LDS.
    const float* row_x = &xs[tid * XSTRIDE];
    int node = 0;
    #pragma unroll
    for (int d = 0; d < DEPTH; ++d) {
        int   f = s_feat[node];
        float t = s_thr[node];
        node = 2 * node + 1 + (row_x[f] > t ? 1 : 0);
    }
    const int leaf = node - NB;

    // Gather leaf value (8 KB table, L1-resident) and write coalesced.
    const float4* v4 = reinterpret_cast<const float4*>(value + (size_t)leaf * 8);
    float4 v0 = v4[0];
    float4 v1 = v4[1];
    float4* o = reinterpret_cast<float4*>(out + (block_row0 + tid) * 8);
    o[0] = v0;
    o[1] = v1;
}

extern "C" void kernel_launch(void* const* d_in, const int* in_sizes, int n_in,
                              void* d_out, int out_size, void* d_ws, size_t ws_size,
                              hipStream_t stream) {
    (void)in_sizes; (void)n_in; (void)d_ws; (void)ws_size; (void)out_size;
    const float* x         = (const float*)d_in[0];
    const int*   feature   = (const int*)d_in[1];
    const float* threshold = (const float*)d_in[2];
    // d_in[3] = cond, d_in[4] = cond_mask — not needed (traversal is equivalent)
    const float* value     = (const float*)d_in[5];
    float*       out       = (float*)d_out;

    dim3 grid(N_ROWS / ROWS_PER_BLOCK);
    dim3 block(256);
    tree_traverse_kernel<<<grid, block, 0, stream>>>(x, feature, threshold, value, out);
}